// Round 3
// baseline (367.191 us; speedup 1.0000x reference)
//
#include <hip/hip_runtime.h>
#include <hip/hip_bf16.h>

#define DEV __device__ __forceinline__

typedef unsigned short u16;
typedef short short8 __attribute__((ext_vector_type(8)));
typedef u16 u16x4 __attribute__((ext_vector_type(4)));
typedef float f32x16 __attribute__((ext_vector_type(16)));

static const int BB = 16;        // batch
static const int NN = 1024;      // tokens
static const int DD = 768;       // dim

DEV u16 f2bf(float f) {
    unsigned u = __builtin_bit_cast(unsigned, f);
    unsigned r = u + 0x7fffu + ((u >> 16) & 1u);
    return (u16)(r >> 16);
}
DEV float h2f(u16 u) { return (float)__builtin_bit_cast(_Float16, u); }
DEV u16 f2h(float f) { return __builtin_bit_cast(u16, (_Float16)f); }

// async 16B global->LDS (direct-to-shared DMA); LDS dest = wave-uniform base + lane*16
DEV void gl_lds16(const void* g, void* l) {
    __builtin_amdgcn_global_load_lds(
        (const __attribute__((address_space(1))) unsigned int*)g,
        (__attribute__((address_space(3))) unsigned int*)l, 16, 0, 0);
}

// compiler memory fence + raw barrier (NO implicit vmcnt drain, unlike __syncthreads)
DEV void fence_bar() {
    asm volatile("" ::: "memory");
    __builtin_amdgcn_s_barrier();
    asm volatile("" ::: "memory");
}
DEV void wait_vm4() { asm volatile("s_waitcnt vmcnt(4)" ::: "memory"); }
DEV void wait_vm8() { asm volatile("s_waitcnt vmcnt(8)" ::: "memory"); }

// ---------------------------------------------------------------------------
// NT-GEMM: C[m,n] = scale * sum_k A[m,k]*B[n,k], A/B bf16 row-major.
// 128x128 tile, BK=64, 4 waves (2x2). Used only for the tiny W-gemm now.
// OM: 0 = store bf16, 1 = store f16, 2 = store f32.
// ---------------------------------------------------------------------------
template<int OM>
__global__ __launch_bounds__(256, 3) void gemm128(
    const u16* __restrict__ Ag, const u16* __restrict__ Bg, void* __restrict__ Cg,
    int K, int N, int zmod,
    long sA0, long sA1, long sB0, long sB1, long sC0, long sC1,
    float scale)
{
    __shared__ u16 As[128 * 64];
    __shared__ u16 Bs[128 * 64];

    int z = blockIdx.z;
    const u16* A = Ag + (long)(z % zmod) * sA0 + (long)(z / zmod) * sA1;
    const u16* B = Bg + (long)(z % zmod) * sB0 + (long)(z / zmod) * sB1;
    u16*   Cu = (u16*)Cg   + (long)(z % zmod) * sC0 + (long)(z / zmod) * sC1;
    float* Cf = (float*)Cg + (long)(z % zmod) * sC0 + (long)(z / zmod) * sC1;

    int tid  = threadIdx.x;
    int lane = tid & 63, wave = tid >> 6;
    int wm = wave & 1, wn = wave >> 1;
    int ln31 = lane & 31, khalf = lane >> 5;

    long m0 = (long)blockIdx.x * 128;
    long n0 = (long)blockIdx.y * 128;

    long aOfs[4], bOfs[4];
    u16 *lA[4], *lB[4];
#pragma unroll
    for (int i = 0; i < 4; i++) {
        int p = tid + i * 256;
        int row = p >> 3, qs = p & 7;
        int q = qs ^ (row & 7);
        aOfs[i] = (m0 + row) * (long)K + q * 8;
        bOfs[i] = (n0 + row) * (long)K + q * 8;
        lA[i] = As + p * 8;
        lB[i] = Bs + p * 8;
    }

    int aoff[2][4], boff[2][4];
#pragma unroll
    for (int t = 0; t < 2; t++) {
        int ra = wm * 64 + t * 32 + ln31;
        int rb = wn * 64 + t * 32 + ln31;
#pragma unroll
        for (int h = 0; h < 4; h++) {
            aoff[t][h] = ra * 64 + (((h * 2 + khalf) ^ (ra & 7)) * 8);
            boff[t][h] = rb * 64 + (((h * 2 + khalf) ^ (rb & 7)) * 8);
        }
    }

    f32x16 acc[2][2] = {};

    for (int k0 = 0; k0 < K; k0 += 64) {
#pragma unroll
        for (int i = 0; i < 4; i++) gl_lds16(A + aOfs[i] + k0, lA[i]);
#pragma unroll
        for (int i = 0; i < 4; i++) gl_lds16(B + bOfs[i] + k0, lB[i]);
        __syncthreads();

#pragma unroll
        for (int h = 0; h < 4; h++) {
            short8 af[2], bfr[2];
#pragma unroll
            for (int t = 0; t < 2; t++) af[t]  = *(const short8*)(As + aoff[t][h]);
#pragma unroll
            for (int t = 0; t < 2; t++) bfr[t] = *(const short8*)(Bs + boff[t][h]);
#pragma unroll
            for (int ti = 0; ti < 2; ti++)
#pragma unroll
                for (int tj = 0; tj < 2; tj++)
                    acc[ti][tj] = __builtin_amdgcn_mfma_f32_32x32x16_bf16(
                        af[ti], bfr[tj], acc[ti][tj], 0, 0, 0);
        }
        __syncthreads();
    }

    long crow = m0 + wm * 64 + 4 * khalf;
    long ccol = n0 + wn * 64 + ln31;
#pragma unroll
    for (int ti = 0; ti < 2; ti++)
#pragma unroll
        for (int tj = 0; tj < 2; tj++)
#pragma unroll
            for (int r = 0; r < 16; r++) {
                long row = crow + ti * 32 + (r & 3) + 8 * (r >> 2);
                long col = ccol + tj * 32;
                float v = acc[ti][tj][r] * scale;
                long idx = row * (long)N + col;
                if constexpr (OM == 0)      Cu[idx] = f2bf(v);
                else if constexpr (OM == 1) Cu[idx] = f2h(v);
                else                        Cf[idx] = v;
            }
}

// ---------------------------------------------------------------------------
// 8-phase 256x256 NT-GEMM (T3+T4 counted-vmcnt schedule + T2 swizzle + T5).
// BK=64, 8 waves (2M x 4N), per-wave out 128x64 = 4x2 of mfma_32x32x16_bf16.
// LDS: 2 buffers x {A.k0, A.k1, B.k0, B.k1} halves of [256 rows][32 k] bf16
// (16KB each) = 128KB total -> 1 block/CU.
// Stage ledger: P1:A1(T1) P2:B1(T1) P3:A0(T2) P4:B0(T2) P5:A1(T2) P6:B1(T2)
// P7:A0(T3) P8:B0(T3); vmcnt(4) only at P4/P8. Last iter clamps K-offset.
// swz != 0: bijective XCD-chunked remap of the linear wg id (T1). Requires
// nwg % 8 == 0 (all our grids: 512, 192).
// ---------------------------------------------------------------------------
template<int OM>
__global__ __launch_bounds__(512, 2) void gemm256(
    const u16* __restrict__ Ag, const u16* __restrict__ Bg, void* __restrict__ Cg,
    int K, int N, int zmod,
    long sA0, long sA1, long sB0, long sB1, long sC0, long sC1,
    float scale, int swz)
{
    __shared__ u16 lds[2][4][8192];   // [buf][0=A.k0 1=A.k1 2=B.k0 3=B.k1]

    int bx = blockIdx.x, by = blockIdx.y, bz = blockIdx.z;
    if (swz) {
        int gx = gridDim.x, gy = gridDim.y;
        int nwg = gx * gy * gridDim.z;
        int lin = bx + gx * (by + gy * bz);
        int sw = (lin & 7) * (nwg >> 3) + (lin >> 3);
        bx = sw % gx; int t = sw / gx;
        by = t % gy;  bz = t / gy;
    }

    int z = bz;
    const u16* A = Ag + (long)(z % zmod) * sA0 + (long)(z / zmod) * sA1;
    const u16* B = Bg + (long)(z % zmod) * sB0 + (long)(z / zmod) * sB1;
    u16*   Cu = (u16*)Cg   + (long)(z % zmod) * sC0 + (long)(z / zmod) * sC1;
    float* Cf = (float*)Cg + (long)(z % zmod) * sC0 + (long)(z / zmod) * sC1;

    int tid  = threadIdx.x;
    int lane = tid & 63, wave = tid >> 6;
    int wm = wave >> 2, wn = wave & 3;          // 2M x 4N
    int ln31 = lane & 31, khalf = lane >> 5;

    long m0 = (long)bx * 256;
    long n0 = (long)by * 256;
    const u16* Apan = A + m0 * (long)K;
    const u16* Bpan = B + n0 * (long)K;

    // staging: 2 chunks/thread per half. chunk p -> row p>>2, global chunk
    // c = (p&3) ^ ((row>>1)&3); LDS dest linear (p*16B).
    long stA[2];
#pragma unroll
    for (int r = 0; r < 2; r++) {
        int p = tid + r * 512;
        int row = p >> 2, c = (p & 3) ^ ((row >> 1) & 3);
        stA[r] = (long)row * K + c * 8;
    }

    // fragment read offsets (u16 units within a half): row rr, k-chunk
    // cs = sl*2 + khalf, swizzled cs ^ ((rr>>1)&3)
    int aoffs[4][2], boffs[2][2];
#pragma unroll
    for (int m = 0; m < 4; m++) {
        int rr = wm * 128 + m * 32 + ln31;
#pragma unroll
        for (int sl = 0; sl < 2; sl++)
            aoffs[m][sl] = rr * 32 + (((sl * 2 + khalf) ^ ((rr >> 1) & 3)) * 8);
    }
#pragma unroll
    for (int n = 0; n < 2; n++) {
        int cc = wn * 64 + n * 32 + ln31;
#pragma unroll
        for (int sl = 0; sl < 2; sl++)
            boffs[n][sl] = cc * 32 + (((sl * 2 + khalf) ^ ((cc >> 1) & 3)) * 8);
    }

    f32x16 acc[4][2] = {};

    int nkt = K >> 6;            // 64-K tiles (even: 12 or 16 here)
    int niter = nkt >> 1;

#define STG(PAN, BUF, HSEL, KT, KH) do {                                   \
    const u16* _s0 = (PAN) + stA[0] + (long)(KT) * 64 + (KH) * 32;         \
    const u16* _s1 = (PAN) + stA[1] + (long)(KT) * 64 + (KH) * 32;         \
    u16* _d = &lds[BUF][HSEL][0] + tid * 8;                                \
    gl_lds16(_s0, _d);                                                     \
    gl_lds16(_s1, _d + 4096);                                              \
} while (0)

#define PH(BUF, S, DOSTG, GUARD) do {                                      \
    short8 av[4], bv[2];                                                   \
    _Pragma("unroll")                                                      \
    for (int m = 0; m < 4; m++)                                            \
        av[m] = *(const short8*)(&lds[BUF][(S) >> 1][aoffs[m][(S) & 1]]);  \
    _Pragma("unroll")                                                      \
    for (int n = 0; n < 2; n++)                                            \
        bv[n] = *(const short8*)(&lds[BUF][2 + ((S) >> 1)][boffs[n][(S) & 1]]); \
    DOSTG;                                                                 \
    if (GUARD) wait_vm4();                                                 \
    fence_bar();                                                           \
    __builtin_amdgcn_s_setprio(1);                                         \
    _Pragma("unroll")                                                      \
    for (int m = 0; m < 4; m++)                                            \
        _Pragma("unroll")                                                  \
        for (int n = 0; n < 2; n++)                                        \
            acc[m][n] = __builtin_amdgcn_mfma_f32_32x32x16_bf16(           \
                av[m], bv[n], acc[m][n], 0, 0, 0);                         \
    __builtin_amdgcn_s_setprio(0);                                         \
    fence_bar();                                                           \
} while (0)

    // prologue: A0(0) B0(0) A1(0) B1(0) A0(1) B0(1); vmcnt(4)
    STG(Apan, 0, 0, 0, 0);
    STG(Bpan, 0, 2, 0, 0);
    STG(Apan, 0, 1, 0, 1);
    STG(Bpan, 0, 3, 0, 1);
    STG(Apan, 1, 0, 1, 0);
    STG(Bpan, 1, 2, 1, 0);
    wait_vm4();
    fence_bar();

    for (int it = 0; it < niter; ++it) {
        int t1 = 2 * it + 1;
        int t2 = 2 * it + 2; int t2c = t2 < nkt ? t2 : nkt - 1;
        int t3 = 2 * it + 3; int t3c = t3 < nkt ? t3 : nkt - 1;
        PH(0, 0, STG(Apan, 1, 1, t1,  1), false);   // stage A1(T1) -> buf1
        PH(0, 1, STG(Bpan, 1, 3, t1,  1), false);   // B1(T1)
        PH(0, 2, STG(Apan, 0, 0, t2c, 0), false);   // A0(T2) -> buf0
        PH(0, 3, STG(Bpan, 0, 2, t2c, 0), true);    // B0(T2); vmcnt(4)
        PH(1, 0, STG(Apan, 0, 1, t2c, 1), false);   // A1(T2)
        PH(1, 1, STG(Bpan, 0, 3, t2c, 1), false);   // B1(T2)
        PH(1, 2, STG(Apan, 1, 0, t3c, 0), false);   // A0(T3) -> buf1
        PH(1, 3, STG(Bpan, 1, 2, t3c, 0), true);    // B0(T3); vmcnt(4)
    }
#undef PH
#undef STG

    long crow = m0 + wm * 128 + 4 * khalf;
    long ccol = n0 + wn * 64 + ln31;
#pragma unroll
    for (int m = 0; m < 4; m++)
#pragma unroll
        for (int n = 0; n < 2; n++)
#pragma unroll
            for (int r = 0; r < 16; r++) {
                long row = crow + m * 32 + (r & 3) + 8 * (r >> 2);
                long col = ccol + n * 32;
                float v = acc[m][n][r] * scale;
                long idx = row * (long)N + col;
                if constexpr (OM == 0)      Cu[idx] = f2bf(v);
                else if constexpr (OM == 1) Cu[idx] = f2h(v);
                else                        Cf[idx] = v;
            }
}

// ---------------------------------------------------------------------------
// 4-phase COARSE variant (A/B vs the 8-phase): same LDS layout / swizzle /
// fragment offsets; phase = one K=32 half (12 ds_read, 16 MFMA, one A+B
// half-pair staged = 4 vm ops, counted vmcnt(8) EVERY phase). Per-iter
// ledger (T0@b0:P1-2, T1@b1:P3-4):
//   P1: stage T1.h1 -> b1.h1   [b1.h1 last read prev P4; needed this P4]
//   P2: stage T2.h0 -> b0.h0   [dead after P1; needed next P1]
//   P3: stage T2.h1 -> b0.h1   [dead after P2; needed next P2]
//   P4: stage T3.h0 -> b1.h0   [dead after P3; needed next P3]
// All stage->read leads = 3 phases; guard at p drains issues <= p-2, so
// reads at p+1 (lead-3 data, staged p-2) are always covered.
// ---------------------------------------------------------------------------
template<int OM>
__global__ __launch_bounds__(512, 2) void gemm256c(
    const u16* __restrict__ Ag, const u16* __restrict__ Bg, void* __restrict__ Cg,
    int K, int N, int zmod,
    long sA0, long sA1, long sB0, long sB1, long sC0, long sC1,
    float scale)
{
    __shared__ u16 lds[2][4][8192];   // [buf][0=A.h0 1=A.h1 2=B.h0 3=B.h1]

    int z = blockIdx.z;
    const u16* A = Ag + (long)(z % zmod) * sA0 + (long)(z / zmod) * sA1;
    const u16* B = Bg + (long)(z % zmod) * sB0 + (long)(z / zmod) * sB1;
    u16*   Cu = (u16*)Cg   + (long)(z % zmod) * sC0 + (long)(z / zmod) * sC1;
    float* Cf = (float*)Cg + (long)(z % zmod) * sC0 + (long)(z / zmod) * sC1;

    int tid  = threadIdx.x;
    int lane = tid & 63, wave = tid >> 6;
    int wm = wave >> 2, wn = wave & 3;          // 2M x 4N
    int ln31 = lane & 31, khalf = lane >> 5;

    long m0 = (long)blockIdx.x * 256;
    long n0 = (long)blockIdx.y * 256;
    const u16* Apan = A + m0 * (long)K;
    const u16* Bpan = B + n0 * (long)K;

    long stA[2];
#pragma unroll
    for (int r = 0; r < 2; r++) {
        int p = tid + r * 512;
        int row = p >> 2, c = (p & 3) ^ ((row >> 1) & 3);
        stA[r] = (long)row * K + c * 8;
    }

    int aoffs[4][2], boffs[2][2];
#pragma unroll
    for (int m = 0; m < 4; m++) {
        int rr = wm * 128 + m * 32 + ln31;
#pragma unroll
        for (int sl = 0; sl < 2; sl++)
            aoffs[m][sl] = rr * 32 + (((sl * 2 + khalf) ^ ((rr >> 1) & 3)) * 8);
    }
#pragma unroll
    for (int n = 0; n < 2; n++) {
        int cc = wn * 64 + n * 32 + ln31;
#pragma unroll
        for (int sl = 0; sl < 2; sl++)
            boffs[n][sl] = cc * 32 + (((sl * 2 + khalf) ^ ((cc >> 1) & 3)) * 8);
    }

    f32x16 acc[4][2] = {};

    int nkt = K >> 6;
    int niter = nkt >> 1;

#define STG2(BUF, H, KT) do {                                              \
    long _ko = (long)(KT) * 64 + (H) * 32;                                 \
    u16* _da = &lds[BUF][H][0] + tid * 8;                                  \
    u16* _db = &lds[BUF][2 + (H)][0] + tid * 8;                            \
    gl_lds16(Apan + stA[0] + _ko, _da);                                    \
    gl_lds16(Apan + stA[1] + _ko, _da + 4096);                             \
    gl_lds16(Bpan + stA[0] + _ko, _db);                                    \
    gl_lds16(Bpan + stA[1] + _ko, _db + 4096);                             \
} while (0)

#define PHC(BUF, H, DOSTG) do {                                            \
    short8 av[4][2], bv[2][2];                                             \
    _Pragma("unroll")                                                      \
    for (int m = 0; m < 4; m++)                                            \
        _Pragma("unroll")                                                  \
        for (int sl = 0; sl < 2; sl++)                                     \
            av[m][sl] = *(const short8*)(&lds[BUF][H][aoffs[m][sl]]);      \
    _Pragma("unroll")                                                      \
    for (int n = 0; n < 2; n++)                                            \
        _Pragma("unroll")                                                  \
        for (int sl = 0; sl < 2; sl++)                                     \
            bv[n][sl] = *(const short8*)(&lds[BUF][2 + (H)][boffs[n][sl]]);\
    DOSTG;                                                                 \
    wait_vm8();                                                            \
    fence_bar();                                                           \
    __builtin_amdgcn_s_setprio(1);                                         \
    _Pragma("unroll")                                                      \
    for (int sl = 0; sl < 2; sl++)                                         \
        _Pragma("unroll")                                                  \
        for (int m = 0; m < 4; m++)                                        \
            _Pragma("unroll")                                              \
            for (int n = 0; n < 2; n++)                                    \
                acc[m][n] = __builtin_amdgcn_mfma_f32_32x32x16_bf16(       \
                    av[m][sl], bv[n][sl], acc[m][n], 0, 0, 0);             \
    __builtin_amdgcn_s_setprio(0);                                         \
    fence_bar();                                                           \
} while (0)

    // prologue: T0.h0, T0.h1, T1.h0 (12 ops); vmcnt(8) -> T0.h0 landed.
    // T0.h1 covered by P1's guard, T1.h0 by P2's guard.
    STG2(0, 0, 0);
    STG2(0, 1, 0);
    STG2(1, 0, 1);
    wait_vm8();
    fence_bar();

    for (int it = 0; it < niter; ++it) {
        int t1 = 2 * it + 1;
        int t2 = 2 * it + 2; int t2c = t2 < nkt ? t2 : nkt - 1;
        int t3 = 2 * it + 3; int t3c = t3 < nkt ? t3 : nkt - 1;
        PHC(0, 0, STG2(1, 1, t1));    // P1: read b0.h0; stage T1.h1
        PHC(0, 1, STG2(0, 0, t2c));   // P2: read b0.h1; stage T2.h0
        PHC(1, 0, STG2(0, 1, t2c));   // P3: read b1.h0; stage T2.h1
        PHC(1, 1, STG2(1, 0, t3c));   // P4: read b1.h1; stage T3.h0
    }
#undef PHC
#undef STG2

    long crow = m0 + wm * 128 + 4 * khalf;
    long ccol = n0 + wn * 64 + ln31;
#pragma unroll
    for (int m = 0; m < 4; m++)
#pragma unroll
        for (int n = 0; n < 2; n++)
#pragma unroll
            for (int r = 0; r < 16; r++) {
                long row = crow + m * 32 + (r & 3) + 8 * (r >> 2);
                long col = ccol + n * 32;
                float v = acc[m][n][r] * scale;
                long idx = row * (long)N + col;
                if constexpr (OM == 0)      Cu[idx] = f2bf(v);
                else if constexpr (OM == 1) Cu[idx] = f2h(v);
                else                        Cf[idx] = v;
            }
}

// ---------------------------------------------------------------------------
// reductions (full 64-lane wave butterflies)
// ---------------------------------------------------------------------------
DEV float wave_red_max(float v) {
#pragma unroll
    for (int o = 32; o; o >>= 1) v = fmaxf(v, __shfl_xor(v, o));
    return v;
}
DEV float wave_red_sum(float v) {
#pragma unroll
    for (int o = 32; o; o >>= 1) v += __shfl_xor(v, o);
    return v;
}
// 4-wave (256-thread) block reductions (used by pos section)
DEV float block_red_max(float v, float* sh) {
    v = wave_red_max(v);
    if ((threadIdx.x & 63) == 0) sh[threadIdx.x >> 6] = v;
    __syncthreads();
    v = fmaxf(fmaxf(sh[0], sh[1]), fmaxf(sh[2], sh[3]));
    __syncthreads();
    return v;
}
DEV float block_red_sum(float v, float* sh) {
    v = wave_red_sum(v);
    if ((threadIdx.x & 63) == 0) sh[threadIdx.x >> 6] = v;
    __syncthreads();
    v = (sh[0] + sh[1]) + (sh[2] + sh[3]);
    __syncthreads();
    return v;
}

// ---------------------------------------------------------------------------
// Fused prep: flat grid, 256-thread blocks:
//   [0, 12288)          conv_y : yb = bf16(y); yT = bf16(y^T)  (float4 loads,
//                                8B packed stores, 32x32 LDS transpose tile)
//   [12288, 18432)      conv_x : xb = bf16(x), 8 f32/thread, 16B/16B
//   [18432, 19456)      pos    : P[n,:] = softmax(coords[n] @ pos_emb[n])
//   [19456, 20032)      prep_u : UTb = bf16(U^T), VT_s = bf16(S_s^2 * U)^T
// ---------------------------------------------------------------------------
__global__ __launch_bounds__(256) void k_prep_all(
    const float* __restrict__ x, const float* __restrict__ y,
    const float* __restrict__ coords, const float* __restrict__ U,
    const float* __restrict__ S1, const float* __restrict__ S2,
    const float* __restrict__ pe,
    u16* __restrict__ xb, u16* __restrict__ yb, u16* __restrict__ yT,
    u16* __restrict__ UTb, u16* __restrict__ VT1, u16* __restrict__ VT2,
    float* __restrict__ P)
{
    __shared__ float shmem[32 * 33];
    int bid = blockIdx.x, tid = threadIdx.x;

    if (bid < 12288) {                         // ---- conv_y (vectorized)
        float (*tile)[33] = (float(*)[33])shmem;
        int b = bid / 768, rem = bid % 768;
        int d0 = (rem % 24) * 32, m0 = (rem / 24) * 32;
        int r = tid >> 3, c4 = (tid & 7) * 4;
        const float* ybase = y + (long)b * NN * DD;
        float4 v = *(const float4*)(ybase + (long)(m0 + r) * DD + d0 + c4);
        u16x4 w4;
        w4[0] = f2bf(v.x); w4[1] = f2bf(v.y); w4[2] = f2bf(v.z); w4[3] = f2bf(v.w);
        *(u16x4*)(yb + (long)b * NN * DD + (long)(m0 + r) * DD + d0 + c4) = w4;
        tile[r][c4 + 0] = v.x; tile[r][c4 + 1] = v.y;
        tile[r][c4 + 2] = v.z; tile[r][c4 + 3] = v.w;
        __syncthreads();
        int d = tid >> 3, mq = (tid & 7) * 4;
        u16x4 o;
        o[0] = f2bf(tile[mq + 0][d]); o[1] = f2bf(tile[mq + 1][d]);
        o[2] = f2bf(tile[mq + 2][d]); o[3] = f2bf(tile[mq + 3][d]);
        *(u16x4*)(yT + (long)b * DD * NN + (long)(d0 + d) * NN + m0 + mq) = o;
        return;
    }
    bid -= 12288;

    if (bid < 6144) {                          // ---- conv_x
        long base = ((long)bid * 256 + tid) * 8;
        float4 f0 = *(const float4*)(x + base);
        float4 f1 = *(const float4*)(x + base + 4);
        short8 w;
        w[0] = (short)f2bf(f0.x); w[1] = (short)f2bf(f0.y);
        w[2] = (short)f2bf(f0.z); w[3] = (short)f2bf(f0.w);
        w[4] = (short)f2bf(f1.x); w[5] = (short)f2bf(f1.y);
        w[6] = (short)f2bf(f1.z); w[7] = (short)f2bf(f1.w);
        *(short8*)(xb + base) = w;
        return;
    }
    bid -= 6144;

    if (bid < 1024) {                          // ---- pos
        int n = bid, t = tid;
        float p6[6];
#pragma unroll
        for (int c = 0; c < 6; c++) p6[c] = pe[n * 6 + c];
        float v[4];
#pragma unroll
        for (int i = 0; i < 4; i++) {
            const float* cp = coords + ((long)n * NN + t * 4 + i) * 6;
            v[i] = p6[0]*cp[0] + p6[1]*cp[1] + p6[2]*cp[2]
                 + p6[3]*cp[3] + p6[4]*cp[4] + p6[5]*cp[5];
        }
        float mx = block_red_max(fmaxf(fmaxf(v[0], v[1]), fmaxf(v[2], v[3])), shmem);
        float e[4], s = 0.f;
#pragma unroll
        for (int i = 0; i < 4; i++) { e[i] = expf(v[i] - mx); s += e[i]; }
        float Z = block_red_sum(s, shmem);
        float inv = 1.f / Z;
        float4 o; o.x = e[0]*inv; o.y = e[1]*inv; o.z = e[2]*inv; o.w = e[3]*inv;
        *(float4*)(P + ((long)n << 10) + t * 4) = o;
        return;
    }
    bid -= 1024;

    {                                          // ---- prep_u (576 blocks)
        float (*tile)[33] = (float(*)[33])shmem;
        int i0 = (bid % 24) * 32, j0 = (bid / 24) * 32;
        int tx = tid & 31, ty = tid >> 5;
#pragma unroll
        for (int r = 0; r < 32; r += 8) {
            int i = i0 + ty + r, j = j0 + tx;
            tile[ty + r][tx] = U[(long)i * DD + j];
        }
        __syncthreads();
        float s1v = S1[i0 + tx];
        float s2v = S2[i0 + tx];
        s1v *= s1v; s2v *= s2v;
#pragma unroll
        for (int r = 0; r < 32; r += 8) {
            int j = j0 + ty + r, i = i0 + tx;
            float v = tile[tx][ty + r];   // U[i][j]
            UTb[(long)j * DD + i] = f2bf(v);
            VT1[(long)j * DD + i] = f2bf(s1v * v);
            VT2[(long)j * DD + i] = f2bf(s2v * v);
        }
    }
}

// ---------------------------------------------------------------------------
// Per (b,n) row: softmax both k, blend with pos, entropy, route, write heat
// and selected blended attn row (bf16 bits) IN-PLACE over S plane k=0.
// grid (B*N), block 64 (ONE wave): 16 m/thread/plane; pure shfl butterflies.
// ---------------------------------------------------------------------------
__global__ __launch_bounds__(64) void k_route(
    u16* __restrict__ S, const float* __restrict__ P,
    const float* __restrict__ gating, const float* __restrict__ temp,
    float* __restrict__ heat)
{
    int bn = blockIdx.x;
    int b = bn >> 10, n = bn & 1023, t = threadIdx.x;
    u16* s1p = S + ((long)(b * 2) << 20) + ((long)n << 10);
    u16* s2p = s1p + (1L << 20);
    const float* pp = P + ((long)n << 10);

    short8 r1a = *(const short8*)(s1p + t * 8);
    short8 r1b = *(const short8*)(s1p + 512 + t * 8);
    short8 r2a = *(const short8*)(s2p + t * 8);
    short8 r2b = *(const short8*)(s2p + 512 + t * 8);
    float4 pv0 = *(const float4*)(pp + t * 8);
    float4 pv1 = *(const float4*)(pp + t * 8 + 4);
    float4 pv2 = *(const float4*)(pp + 512 + t * 8);
    float4 pv3 = *(const float4*)(pp + 512 + t * 8 + 4);

    float s1[16], s2[16], p8[16];
#pragma unroll
    for (int i = 0; i < 8; i++) {
        s1[i]     = h2f((u16)r1a[i]);
        s1[i + 8] = h2f((u16)r1b[i]);
        s2[i]     = h2f((u16)r2a[i]);
        s2[i + 8] = h2f((u16)r2b[i]);
    }
    p8[0]=pv0.x;  p8[1]=pv0.y;  p8[2]=pv0.z;  p8[3]=pv0.w;
    p8[4]=pv1.x;  p8[5]=pv1.y;  p8[6]=pv1.z;  p8[7]=pv1.w;
    p8[8]=pv2.x;  p8[9]=pv2.y;  p8[10]=pv2.z; p8[11]=pv2.w;
    p8[12]=pv3.x; p8[13]=pv3.y; p8[14]=pv3.z; p8[15]=pv3.w;

    float m1 = s1[0], m2 = s2[0];
#pragma unroll
    for (int i = 1; i < 16; i++) { m1 = fmaxf(m1, s1[i]); m2 = fmaxf(m2, s2[i]); }
    float mx1 = wave_red_max(m1);
    float mx2 = wave_red_max(m2);

    float e1[16], e2[16], z1 = 0.f, z2 = 0.f;
#pragma unroll
    for (int i = 0; i < 16; i++) {
        e1[i] = expf(s1[i] - mx1); z1 += e1[i];
        e2[i] = expf(s2[i] - mx2); z2 += e2[i];
    }
    float Z1 = wave_red_sum(z1);
    float Z2 = wave_red_sum(z2);

    float g = 1.f / (1.f + expf(-gating[0]));
    float c1 = (1.f - g) / Z1, c2 = (1.f - g) / Z2;

    float a1[16], a2[16], hh1 = 0.f, hh2 = 0.f;
#pragma unroll
    for (int i = 0; i < 16; i++) {
        a1[i] = e1[i] * c1 + g * p8[i];
        a2[i] = e2[i] * c2 + g * p8[i];
        hh1 -= a1[i] * logf(a1[i] + 1e-8f);
        hh2 -= a2[i] * logf(a2[i] + 1e-8f);
    }
    float H1 = wave_red_sum(hh1);
    float H2 = wave_red_sum(hh2);

    float tv = temp[0];
    float hm0 = 2.f - 2.f / (1.f + expf(-tv * H1));
    float hm1 = 2.f - 2.f / (1.f + expf(-tv * H2));
    int ks = (hm0 >= hm1) ? 0 : 1;
    if (t == 0) heat[bn] = ks ? hm1 : hm0;

    short8 w0, w1;
#pragma unroll
    for (int i = 0; i < 8; i++) {
        w0[i] = (short)f2bf(ks ? a2[i] : a1[i]);
        w1[i] = (short)f2bf(ks ? a2[i + 8] : a1[i + 8]);
    }
    *(short8*)(s1p + t * 8) = w0;
    *(short8*)(s1p + 512 + t * 8) = w1;
}

// ---------------------------------------------------------------------------
extern "C" void kernel_launch(void* const* d_in, const int* in_sizes, int n_in,
                              void* d_out, int out_size, void* d_ws, size_t ws_size,
                              hipStream_t stream)
{
    (void)in_sizes; (void)n_in; (void)out_size; (void)ws_size;
    const float* x      = (const float*)d_in[0];
    const float* y      = (const float*)d_in[1];
    const float* coords = (const float*)d_in[2];
    const float* U      = (const float*)d_in[3];
    const float* S1     = (const float*)d_in[4];
    const float* S2     = (const float*)d_in[5];
    const float* gating = (const float*)d_in[6];
    const float* temp   = (const float*)d_in[7];
    const float* pose   = (const float*)d_in[8];

    float* out  = (float*)d_out;
    float* heat = out + (long)BB * NN * DD;

    char* w = (char*)d_ws;
    u16* UTb = (u16*)w;  w += (long)DD * DD * 2;            //  1.125 MB
    u16* VT  = (u16*)w;  w += (long)2 * DD * DD * 2;        //  2.25 MB (VT1,VT2)
    u16* W2  = (u16*)w;  w += (long)2 * DD * DD * 2;        //  2.25 MB (W1,W2)
    u16* x12 = (u16*)w;  w += (long)2 * BB * NN * DD * 2;   // 48 MB
    u16* yb  = (u16*)w;  w += (long)BB * NN * DD * 2;       // 24 MB
    u16* yT  = (u16*)w;  w += (long)BB * DD * NN * 2;       // 24 MB
    u16* S   = (u16*)w;  w += (long)BB * 2 * NN * NN * 2;   // 64 MB
    float* P = (float*)w;                                   //  4 MB

    // xb (bf16 x, 24 MB) lives in the S region: S is written only by the
    // S-GEMM, which is stream-ordered AFTER the x12-GEMM's last read of xb.
    u16* xb = S;

    const long MBN = (long)BB * NN * DD;       // x1/x2 plane elements
    const long BND = (long)NN * DD;            // per-b x/y plane
    const long SPL = (long)NN * NN;            // score plane
    const long DSQ = (long)DD * DD;

    // fused prep: conv_y | conv_x | pos | prep_u
    k_prep_all<<<dim3(20032), dim3(256), 0, stream>>>(
        x, y, coords, U, S1, S2, pose, xb, yb, yT, UTb, VT, VT + DSQ, P);

    // W_s[i,j] = sum_t U[t,i] S_s[t]^2 U[t,j]  (NT: A=UTb, B=VT_s); z = s
    gemm128<0><<<dim3(DD / 128, DD / 128, 2), dim3(256), 0, stream>>>(
        UTb, VT, W2, DD, DD, 2,
        0L, 0L, DSQ, 0L, DSQ, 0L, 1.0f);

    // x12[s] = xb @ W_s  (A bf16 shared across z, W symmetric); z = s
    // 4-phase COARSE variant (A/B experiment); no XCD swizzle (A-sharers
    // already co-XCD under linear dispatch).
    gemm256c<0><<<dim3(BB * NN / 256, DD / 256, 2), dim3(512), 0, stream>>>(
        xb, W2, x12, DD, DD, 2,
        0L, 0L, DSQ, 0L, MBN, 0L, 1.0f);

    // S[b,k] = scale * x_k[b] @ y[b]^T   (C f16); z = b*2 + k
    // 8-phase + XCD swizzle (each XCD gets 4 contiguous z-planes)
    gemm256<1><<<dim3(NN / 256, NN / 256, BB * 2), dim3(512), 0, stream>>>(
        x12, yb, S, DD, NN, 2,
        MBN, BND, 0L, BND, SPL, 2 * SPL, 0.036084391824351615f, 1);

    // softmax + blend + entropy + route; attn_c (bf16) in-place at k=0 plane
    k_route<<<dim3(BB * NN), dim3(64), 0, stream>>>(S, P, gating, temp, heat);

    // out[b] = attn_c[b] @ y[b]   (A bf16 in S k=0 plane, B = yT bf16, C f32)
    gemm256<2><<<dim3(NN / 256, DD / 256, BB), dim3(512), 0, stream>>>(
        S, yT, out, NN, DD, 1,
        0L, 2 * SPL, 0L, BND, 0L, BND, 1.0f, 1);
}

// Round 4
// 354.686 us; speedup vs baseline: 1.0353x; 1.0353x over previous
//
#include <hip/hip_runtime.h>
#include <hip/hip_bf16.h>

#define DEV __device__ __forceinline__

typedef unsigned short u16;
typedef short short8 __attribute__((ext_vector_type(8)));
typedef u16 u16x4 __attribute__((ext_vector_type(4)));
typedef float f32x16 __attribute__((ext_vector_type(16)));

static const int BB = 16;        // batch
static const int NN = 1024;      // tokens
static const int DD = 768;       // dim

DEV u16 f2bf(float f) {
    unsigned u = __builtin_bit_cast(unsigned, f);
    unsigned r = u + 0x7fffu + ((u >> 16) & 1u);
    return (u16)(r >> 16);
}
DEV float h2f(u16 u) { return (float)__builtin_bit_cast(_Float16, u); }
DEV u16 f2h(float f) { return __builtin_bit_cast(u16, (_Float16)f); }

// async 16B global->LDS (direct-to-shared DMA); LDS dest = wave-uniform base + lane*16
DEV void gl_lds16(const void* g, void* l) {
    __builtin_amdgcn_global_load_lds(
        (const __attribute__((address_space(1))) unsigned int*)g,
        (__attribute__((address_space(3))) unsigned int*)l, 16, 0, 0);
}

// compiler memory fence + raw barrier (NO implicit vmcnt drain, unlike __syncthreads)
DEV void fence_bar() {
    asm volatile("" ::: "memory");
    __builtin_amdgcn_s_barrier();
    asm volatile("" ::: "memory");
}
DEV void wait_vm4() { asm volatile("s_waitcnt vmcnt(4)" ::: "memory"); }

// ---------------------------------------------------------------------------
// NT-GEMM: C[m,n] = scale * sum_k A[m,k]*B[n,k], A/B bf16 row-major.
// 128x128 tile, BK=64, 4 waves (2x2). Used only for the tiny W-gemm now.
// OM: 0 = store bf16, 1 = store f16, 2 = store f32.
// ---------------------------------------------------------------------------
template<int OM>
__global__ __launch_bounds__(256, 3) void gemm128(
    const u16* __restrict__ Ag, const u16* __restrict__ Bg, void* __restrict__ Cg,
    int K, int N, int zmod,
    long sA0, long sA1, long sB0, long sB1, long sC0, long sC1,
    float scale)
{
    __shared__ u16 As[128 * 64];
    __shared__ u16 Bs[128 * 64];

    int z = blockIdx.z;
    const u16* A = Ag + (long)(z % zmod) * sA0 + (long)(z / zmod) * sA1;
    const u16* B = Bg + (long)(z % zmod) * sB0 + (long)(z / zmod) * sB1;
    u16*   Cu = (u16*)Cg   + (long)(z % zmod) * sC0 + (long)(z / zmod) * sC1;
    float* Cf = (float*)Cg + (long)(z % zmod) * sC0 + (long)(z / zmod) * sC1;

    int tid  = threadIdx.x;
    int lane = tid & 63, wave = tid >> 6;
    int wm = wave & 1, wn = wave >> 1;
    int ln31 = lane & 31, khalf = lane >> 5;

    long m0 = (long)blockIdx.x * 128;
    long n0 = (long)blockIdx.y * 128;

    long aOfs[4], bOfs[4];
    u16 *lA[4], *lB[4];
#pragma unroll
    for (int i = 0; i < 4; i++) {
        int p = tid + i * 256;
        int row = p >> 3, qs = p & 7;
        int q = qs ^ (row & 7);
        aOfs[i] = (m0 + row) * (long)K + q * 8;
        bOfs[i] = (n0 + row) * (long)K + q * 8;
        lA[i] = As + p * 8;
        lB[i] = Bs + p * 8;
    }

    int aoff[2][4], boff[2][4];
#pragma unroll
    for (int t = 0; t < 2; t++) {
        int ra = wm * 64 + t * 32 + ln31;
        int rb = wn * 64 + t * 32 + ln31;
#pragma unroll
        for (int h = 0; h < 4; h++) {
            aoff[t][h] = ra * 64 + (((h * 2 + khalf) ^ (ra & 7)) * 8);
            boff[t][h] = rb * 64 + (((h * 2 + khalf) ^ (rb & 7)) * 8);
        }
    }

    f32x16 acc[2][2] = {};

    for (int k0 = 0; k0 < K; k0 += 64) {
#pragma unroll
        for (int i = 0; i < 4; i++) gl_lds16(A + aOfs[i] + k0, lA[i]);
#pragma unroll
        for (int i = 0; i < 4; i++) gl_lds16(B + bOfs[i] + k0, lB[i]);
        __syncthreads();

#pragma unroll
        for (int h = 0; h < 4; h++) {
            short8 af[2], bfr[2];
#pragma unroll
            for (int t = 0; t < 2; t++) af[t]  = *(const short8*)(As + aoff[t][h]);
#pragma unroll
            for (int t = 0; t < 2; t++) bfr[t] = *(const short8*)(Bs + boff[t][h]);
#pragma unroll
            for (int ti = 0; ti < 2; ti++)
#pragma unroll
                for (int tj = 0; tj < 2; tj++)
                    acc[ti][tj] = __builtin_amdgcn_mfma_f32_32x32x16_bf16(
                        af[ti], bfr[tj], acc[ti][tj], 0, 0, 0);
        }
        __syncthreads();
    }

    long crow = m0 + wm * 64 + 4 * khalf;
    long ccol = n0 + wn * 64 + ln31;
#pragma unroll
    for (int ti = 0; ti < 2; ti++)
#pragma unroll
        for (int tj = 0; tj < 2; tj++)
#pragma unroll
            for (int r = 0; r < 16; r++) {
                long row = crow + ti * 32 + (r & 3) + 8 * (r >> 2);
                long col = ccol + tj * 32;
                float v = acc[ti][tj][r] * scale;
                long idx = row * (long)N + col;
                if constexpr (OM == 0)      Cu[idx] = f2bf(v);
                else if constexpr (OM == 1) Cu[idx] = f2h(v);
                else                        Cf[idx] = v;
            }
}

// ---------------------------------------------------------------------------
// 8-phase 256x256 NT-GEMM (T3+T4 counted-vmcnt schedule + T2 swizzle + T5).
// BK=64, 8 waves (2M x 4N), per-wave out 128x64 = 4x2 of mfma_32x32x16_bf16.
// LDS: 2 buffers x {A.k0, A.k1, B.k0, B.k1} halves of [256 rows][32 k] bf16
// (16KB each) = 128KB total -> 1 block/CU.
// Stage ledger: P1:A1(T1) P2:B1(T1) P3:A0(T2) P4:B0(T2) P5:A1(T2) P6:B1(T2)
// P7:A0(T3) P8:B0(T3); vmcnt(4) only at P4/P8. Last iter clamps K-offset.
// swz != 0: bijective XCD-chunked remap of the linear wg id (T1); needs
// nwg % 8 == 0 (our grids: 384, 256, 256, 192).
// ---------------------------------------------------------------------------
template<int OM>
__global__ __launch_bounds__(512, 2) void gemm256(
    const u16* __restrict__ Ag, const u16* __restrict__ Bg, void* __restrict__ Cg,
    int K, int N, int zmod,
    long sA0, long sA1, long sB0, long sB1, long sC0, long sC1,
    float scale, int swz)
{
    __shared__ u16 lds[2][4][8192];   // [buf][0=A.k0 1=A.k1 2=B.k0 3=B.k1]

    int bx = blockIdx.x, by = blockIdx.y, bz = blockIdx.z;
    if (swz) {
        int gx = gridDim.x, gy = gridDim.y;
        int nwg = gx * gy * gridDim.z;
        int lin = bx + gx * (by + gy * bz);
        int sw = (lin & 7) * (nwg >> 3) + (lin >> 3);
        bx = sw % gx; int t = sw / gx;
        by = t % gy;  bz = t / gy;
    }

    int z = bz;
    const u16* A = Ag + (long)(z % zmod) * sA0 + (long)(z / zmod) * sA1;
    const u16* B = Bg + (long)(z % zmod) * sB0 + (long)(z / zmod) * sB1;
    u16*   Cu = (u16*)Cg   + (long)(z % zmod) * sC0 + (long)(z / zmod) * sC1;
    float* Cf = (float*)Cg + (long)(z % zmod) * sC0 + (long)(z / zmod) * sC1;

    int tid  = threadIdx.x;
    int lane = tid & 63, wave = tid >> 6;
    int wm = wave >> 2, wn = wave & 3;          // 2M x 4N
    int ln31 = lane & 31, khalf = lane >> 5;

    long m0 = (long)bx * 256;
    long n0 = (long)by * 256;
    const u16* Apan = A + m0 * (long)K;
    const u16* Bpan = B + n0 * (long)K;

    // staging: 2 chunks/thread per half. chunk p -> row p>>2, global chunk
    // c = (p&3) ^ ((row>>1)&3); LDS dest linear (p*16B).
    long stA[2];
#pragma unroll
    for (int r = 0; r < 2; r++) {
        int p = tid + r * 512;
        int row = p >> 2, c = (p & 3) ^ ((row >> 1) & 3);
        stA[r] = (long)row * K + c * 8;
    }

    // fragment read offsets (u16 units within a half): row rr, k-chunk
    // cs = sl*2 + khalf, swizzled cs ^ ((rr>>1)&3)
    int aoffs[4][2], boffs[2][2];
#pragma unroll
    for (int m = 0; m < 4; m++) {
        int rr = wm * 128 + m * 32 + ln31;
#pragma unroll
        for (int sl = 0; sl < 2; sl++)
            aoffs[m][sl] = rr * 32 + (((sl * 2 + khalf) ^ ((rr >> 1) & 3)) * 8);
    }
#pragma unroll
    for (int n = 0; n < 2; n++) {
        int cc = wn * 64 + n * 32 + ln31;
#pragma unroll
        for (int sl = 0; sl < 2; sl++)
            boffs[n][sl] = cc * 32 + (((sl * 2 + khalf) ^ ((cc >> 1) & 3)) * 8);
    }

    f32x16 acc[4][2] = {};

    int nkt = K >> 6;            // 64-K tiles (even: 12 or 16 here)
    int niter = nkt >> 1;

#define STG(PAN, BUF, HSEL, KT, KH) do {                                   \
    const u16* _s0 = (PAN) + stA[0] + (long)(KT) * 64 + (KH) * 32;         \
    const u16* _s1 = (PAN) + stA[1] + (long)(KT) * 64 + (KH) * 32;         \
    u16* _d = &lds[BUF][HSEL][0] + tid * 8;                                \
    gl_lds16(_s0, _d);                                                     \
    gl_lds16(_s1, _d + 4096);                                              \
} while (0)

#define PH(BUF, S, DOSTG, GUARD) do {                                      \
    short8 av[4], bv[2];                                                   \
    _Pragma("unroll")                                                      \
    for (int m = 0; m < 4; m++)                                            \
        av[m] = *(const short8*)(&lds[BUF][(S) >> 1][aoffs[m][(S) & 1]]);  \
    _Pragma("unroll")                                                      \
    for (int n = 0; n < 2; n++)                                            \
        bv[n] = *(const short8*)(&lds[BUF][2 + ((S) >> 1)][boffs[n][(S) & 1]]); \
    DOSTG;                                                                 \
    if (GUARD) wait_vm4();                                                 \
    fence_bar();                                                           \
    __builtin_amdgcn_s_setprio(1);                                         \
    _Pragma("unroll")                                                      \
    for (int m = 0; m < 4; m++)                                            \
        _Pragma("unroll")                                                  \
        for (int n = 0; n < 2; n++)                                        \
            acc[m][n] = __builtin_amdgcn_mfma_f32_32x32x16_bf16(           \
                av[m], bv[n], acc[m][n], 0, 0, 0);                         \
    __builtin_amdgcn_s_setprio(0);                                         \
    fence_bar();                                                           \
} while (0)

    // prologue: A0(0) B0(0) A1(0) B1(0) A0(1) B0(1); vmcnt(4)
    STG(Apan, 0, 0, 0, 0);
    STG(Bpan, 0, 2, 0, 0);
    STG(Apan, 0, 1, 0, 1);
    STG(Bpan, 0, 3, 0, 1);
    STG(Apan, 1, 0, 1, 0);
    STG(Bpan, 1, 2, 1, 0);
    wait_vm4();
    fence_bar();

    for (int it = 0; it < niter; ++it) {
        int t1 = 2 * it + 1;
        int t2 = 2 * it + 2; int t2c = t2 < nkt ? t2 : nkt - 1;
        int t3 = 2 * it + 3; int t3c = t3 < nkt ? t3 : nkt - 1;
        PH(0, 0, STG(Apan, 1, 1, t1,  1), false);   // stage A1(T1) -> buf1
        PH(0, 1, STG(Bpan, 1, 3, t1,  1), false);   // B1(T1)
        PH(0, 2, STG(Apan, 0, 0, t2c, 0), false);   // A0(T2) -> buf0
        PH(0, 3, STG(Bpan, 0, 2, t2c, 0), true);    // B0(T2); vmcnt(4)
        PH(1, 0, STG(Apan, 0, 1, t2c, 1), false);   // A1(T2)
        PH(1, 1, STG(Bpan, 0, 3, t2c, 1), false);   // B1(T2)
        PH(1, 2, STG(Apan, 1, 0, t3c, 0), false);   // A0(T3) -> buf1
        PH(1, 3, STG(Bpan, 1, 2, t3c, 0), true);    // B0(T3); vmcnt(4)
    }
#undef PH
#undef STG

    long crow = m0 + wm * 128 + 4 * khalf;
    long ccol = n0 + wn * 64 + ln31;
#pragma unroll
    for (int m = 0; m < 4; m++)
#pragma unroll
        for (int n = 0; n < 2; n++)
#pragma unroll
            for (int r = 0; r < 16; r++) {
                long row = crow + m * 32 + (r & 3) + 8 * (r >> 2);
                long col = ccol + n * 32;
                float v = acc[m][n][r] * scale;
                long idx = row * (long)N + col;
                if constexpr (OM == 0)      Cu[idx] = f2bf(v);
                else if constexpr (OM == 1) Cu[idx] = f2h(v);
                else                        Cf[idx] = v;
            }
}

// ---------------------------------------------------------------------------
// reductions (full 64-lane wave butterflies)
// ---------------------------------------------------------------------------
DEV float wave_red_max(float v) {
#pragma unroll
    for (int o = 32; o; o >>= 1) v = fmaxf(v, __shfl_xor(v, o));
    return v;
}
DEV float wave_red_sum(float v) {
#pragma unroll
    for (int o = 32; o; o >>= 1) v += __shfl_xor(v, o);
    return v;
}
// 4-wave (256-thread) block reductions (used by pos section)
DEV float block_red_max(float v, float* sh) {
    v = wave_red_max(v);
    if ((threadIdx.x & 63) == 0) sh[threadIdx.x >> 6] = v;
    __syncthreads();
    v = fmaxf(fmaxf(sh[0], sh[1]), fmaxf(sh[2], sh[3]));
    __syncthreads();
    return v;
}
DEV float block_red_sum(float v, float* sh) {
    v = wave_red_sum(v);
    if ((threadIdx.x & 63) == 0) sh[threadIdx.x >> 6] = v;
    __syncthreads();
    v = (sh[0] + sh[1]) + (sh[2] + sh[3]);
    __syncthreads();
    return v;
}

// ---------------------------------------------------------------------------
// Fused prep: flat grid, 256-thread blocks:
//   [0, 12288)          conv_y : yb = bf16(y); yT = bf16(y^T)  (float4 loads,
//                                8B packed stores, 32x32 LDS transpose tile)
//   [12288, 18432)      conv_x : xb = bf16(x), 8 f32/thread, 16B/16B
//   [18432, 19456)      pos    : P[n,:] = softmax(coords[n] @ pos_emb[n])
//   [19456, 20032)      prep_u : UTb = bf16(U^T), VT_s = bf16(S_s^2 * U)^T
// ---------------------------------------------------------------------------
__global__ __launch_bounds__(256) void k_prep_all(
    const float* __restrict__ x, const float* __restrict__ y,
    const float* __restrict__ coords, const float* __restrict__ U,
    const float* __restrict__ S1, const float* __restrict__ S2,
    const float* __restrict__ pe,
    u16* __restrict__ xb, u16* __restrict__ yb, u16* __restrict__ yT,
    u16* __restrict__ UTb, u16* __restrict__ VT1, u16* __restrict__ VT2,
    float* __restrict__ P)
{
    __shared__ float shmem[32 * 33];
    int bid = blockIdx.x, tid = threadIdx.x;

    if (bid < 12288) {                         // ---- conv_y (vectorized)
        float (*tile)[33] = (float(*)[33])shmem;
        int b = bid / 768, rem = bid % 768;
        int d0 = (rem % 24) * 32, m0 = (rem / 24) * 32;
        int r = tid >> 3, c4 = (tid & 7) * 4;
        const float* ybase = y + (long)b * NN * DD;
        float4 v = *(const float4*)(ybase + (long)(m0 + r) * DD + d0 + c4);
        u16x4 w4;
        w4[0] = f2bf(v.x); w4[1] = f2bf(v.y); w4[2] = f2bf(v.z); w4[3] = f2bf(v.w);
        *(u16x4*)(yb + (long)b * NN * DD + (long)(m0 + r) * DD + d0 + c4) = w4;
        tile[r][c4 + 0] = v.x; tile[r][c4 + 1] = v.y;
        tile[r][c4 + 2] = v.z; tile[r][c4 + 3] = v.w;
        __syncthreads();
        int d = tid >> 3, mq = (tid & 7) * 4;
        u16x4 o;
        o[0] = f2bf(tile[mq + 0][d]); o[1] = f2bf(tile[mq + 1][d]);
        o[2] = f2bf(tile[mq + 2][d]); o[3] = f2bf(tile[mq + 3][d]);
        *(u16x4*)(yT + (long)b * DD * NN + (long)(d0 + d) * NN + m0 + mq) = o;
        return;
    }
    bid -= 12288;

    if (bid < 6144) {                          // ---- conv_x
        long base = ((long)bid * 256 + tid) * 8;
        float4 f0 = *(const float4*)(x + base);
        float4 f1 = *(const float4*)(x + base + 4);
        short8 w;
        w[0] = (short)f2bf(f0.x); w[1] = (short)f2bf(f0.y);
        w[2] = (short)f2bf(f0.z); w[3] = (short)f2bf(f0.w);
        w[4] = (short)f2bf(f1.x); w[5] = (short)f2bf(f1.y);
        w[6] = (short)f2bf(f1.z); w[7] = (short)f2bf(f1.w);
        *(short8*)(xb + base) = w;
        return;
    }
    bid -= 6144;

    if (bid < 1024) {                          // ---- pos
        int n = bid, t = tid;
        float p6[6];
#pragma unroll
        for (int c = 0; c < 6; c++) p6[c] = pe[n * 6 + c];
        float v[4];
#pragma unroll
        for (int i = 0; i < 4; i++) {
            const float* cp = coords + ((long)n * NN + t * 4 + i) * 6;
            v[i] = p6[0]*cp[0] + p6[1]*cp[1] + p6[2]*cp[2]
                 + p6[3]*cp[3] + p6[4]*cp[4] + p6[5]*cp[5];
        }
        float mx = block_red_max(fmaxf(fmaxf(v[0], v[1]), fmaxf(v[2], v[3])), shmem);
        float e[4], s = 0.f;
#pragma unroll
        for (int i = 0; i < 4; i++) { e[i] = __expf(v[i] - mx); s += e[i]; }
        float Z = block_red_sum(s, shmem);
        float inv = 1.f / Z;
        float4 o; o.x = e[0]*inv; o.y = e[1]*inv; o.z = e[2]*inv; o.w = e[3]*inv;
        *(float4*)(P + ((long)n << 10) + t * 4) = o;
        return;
    }
    bid -= 1024;

    {                                          // ---- prep_u (576 blocks)
        float (*tile)[33] = (float(*)[33])shmem;
        int i0 = (bid % 24) * 32, j0 = (bid / 24) * 32;
        int tx = tid & 31, ty = tid >> 5;
#pragma unroll
        for (int r = 0; r < 32; r += 8) {
            int i = i0 + ty + r, j = j0 + tx;
            tile[ty + r][tx] = U[(long)i * DD + j];
        }
        __syncthreads();
        float s1v = S1[i0 + tx];
        float s2v = S2[i0 + tx];
        s1v *= s1v; s2v *= s2v;
#pragma unroll
        for (int r = 0; r < 32; r += 8) {
            int j = j0 + ty + r, i = i0 + tx;
            float v = tile[tx][ty + r];   // U[i][j]
            UTb[(long)j * DD + i] = f2bf(v);
            VT1[(long)j * DD + i] = f2bf(s1v * v);
            VT2[(long)j * DD + i] = f2bf(s2v * v);
        }
    }
}

// ---------------------------------------------------------------------------
// Per (b,n) row: softmax both k, blend with pos, entropy, route, write heat
// and selected blended attn row (bf16 bits) IN-PLACE over S plane k=0.
// grid (B*N/2), block 128 = TWO independent waves, each owning one row:
// 16 m/thread/plane, pure 64-lane shfl butterflies, no LDS, no barriers.
// Fast transcendentals (__expf/__logf): rel err ~5e-7 << bf16 storage error.
// ---------------------------------------------------------------------------
__global__ __launch_bounds__(128) void k_route(
    u16* __restrict__ S, const float* __restrict__ P,
    const float* __restrict__ gating, const float* __restrict__ temp,
    float* __restrict__ heat)
{
    int bn = (blockIdx.x << 1) | (threadIdx.x >> 6);
    int t = threadIdx.x & 63;
    int b = bn >> 10, n = bn & 1023;
    u16* s1p = S + ((long)(b * 2) << 20) + ((long)n << 10);
    u16* s2p = s1p + (1L << 20);
    const float* pp = P + ((long)n << 10);

    short8 r1a = *(const short8*)(s1p + t * 8);
    short8 r1b = *(const short8*)(s1p + 512 + t * 8);
    short8 r2a = *(const short8*)(s2p + t * 8);
    short8 r2b = *(const short8*)(s2p + 512 + t * 8);
    float4 pv0 = *(const float4*)(pp + t * 8);
    float4 pv1 = *(const float4*)(pp + t * 8 + 4);
    float4 pv2 = *(const float4*)(pp + 512 + t * 8);
    float4 pv3 = *(const float4*)(pp + 512 + t * 8 + 4);

    float s1[16], s2[16], p8[16];
#pragma unroll
    for (int i = 0; i < 8; i++) {
        s1[i]     = h2f((u16)r1a[i]);
        s1[i + 8] = h2f((u16)r1b[i]);
        s2[i]     = h2f((u16)r2a[i]);
        s2[i + 8] = h2f((u16)r2b[i]);
    }
    p8[0]=pv0.x;  p8[1]=pv0.y;  p8[2]=pv0.z;  p8[3]=pv0.w;
    p8[4]=pv1.x;  p8[5]=pv1.y;  p8[6]=pv1.z;  p8[7]=pv1.w;
    p8[8]=pv2.x;  p8[9]=pv2.y;  p8[10]=pv2.z; p8[11]=pv2.w;
    p8[12]=pv3.x; p8[13]=pv3.y; p8[14]=pv3.z; p8[15]=pv3.w;

    float m1 = s1[0], m2 = s2[0];
#pragma unroll
    for (int i = 1; i < 16; i++) { m1 = fmaxf(m1, s1[i]); m2 = fmaxf(m2, s2[i]); }
    float mx1 = wave_red_max(m1);
    float mx2 = wave_red_max(m2);

    float e1[16], e2[16], z1 = 0.f, z2 = 0.f;
#pragma unroll
    for (int i = 0; i < 16; i++) {
        e1[i] = __expf(s1[i] - mx1); z1 += e1[i];
        e2[i] = __expf(s2[i] - mx2); z2 += e2[i];
    }
    float Z1 = wave_red_sum(z1);
    float Z2 = wave_red_sum(z2);

    float g = 1.f / (1.f + __expf(-gating[0]));
    float c1 = (1.f - g) / Z1, c2 = (1.f - g) / Z2;

    float a1[16], a2[16], hh1 = 0.f, hh2 = 0.f;
#pragma unroll
    for (int i = 0; i < 16; i++) {
        a1[i] = e1[i] * c1 + g * p8[i];
        a2[i] = e2[i] * c2 + g * p8[i];
        hh1 -= a1[i] * __logf(a1[i] + 1e-8f);
        hh2 -= a2[i] * __logf(a2[i] + 1e-8f);
    }
    float H1 = wave_red_sum(hh1);
    float H2 = wave_red_sum(hh2);

    float tv = temp[0];
    float hm0 = 2.f - 2.f / (1.f + __expf(-tv * H1));
    float hm1 = 2.f - 2.f / (1.f + __expf(-tv * H2));
    int ks = (hm0 >= hm1) ? 0 : 1;
    if (t == 0) heat[bn] = ks ? hm1 : hm0;

    short8 w0, w1;
#pragma unroll
    for (int i = 0; i < 8; i++) {
        w0[i] = (short)f2bf(ks ? a2[i] : a1[i]);
        w1[i] = (short)f2bf(ks ? a2[i + 8] : a1[i + 8]);
    }
    *(short8*)(s1p + t * 8) = w0;
    *(short8*)(s1p + 512 + t * 8) = w1;
}

// ---------------------------------------------------------------------------
extern "C" void kernel_launch(void* const* d_in, const int* in_sizes, int n_in,
                              void* d_out, int out_size, void* d_ws, size_t ws_size,
                              hipStream_t stream)
{
    (void)in_sizes; (void)n_in; (void)out_size; (void)ws_size;
    const float* x      = (const float*)d_in[0];
    const float* y      = (const float*)d_in[1];
    const float* coords = (const float*)d_in[2];
    const float* U      = (const float*)d_in[3];
    const float* S1     = (const float*)d_in[4];
    const float* S2     = (const float*)d_in[5];
    const float* gating = (const float*)d_in[6];
    const float* temp   = (const float*)d_in[7];
    const float* pose   = (const float*)d_in[8];

    float* out  = (float*)d_out;
    float* heat = out + (long)BB * NN * DD;

    char* w = (char*)d_ws;
    u16* UTb = (u16*)w;  w += (long)DD * DD * 2;            //  1.125 MB
    u16* VT  = (u16*)w;  w += (long)2 * DD * DD * 2;        //  2.25 MB (VT1,VT2)
    u16* W2  = (u16*)w;  w += (long)2 * DD * DD * 2;        //  2.25 MB (W1,W2)
    u16* x12 = (u16*)w;  w += (long)2 * BB * NN * DD * 2;   // 48 MB
    u16* yb  = (u16*)w;  w += (long)BB * NN * DD * 2;       // 24 MB
    u16* yT  = (u16*)w;  w += (long)BB * DD * NN * 2;       // 24 MB
    u16* S   = (u16*)w;  w += (long)BB * 2 * NN * NN * 2;   // 64 MB
    float* P = (float*)w;                                   //  4 MB

    // xb (bf16 x, 24 MB) lives in the S region: S is written only by the
    // S-GEMM, which is stream-ordered AFTER the x12-GEMM's last read of xb.
    u16* xb = S;

    const long MBN = (long)BB * NN * DD;       // x1/x2 plane elements
    const long BND = (long)NN * DD;            // per-b x/y plane
    const long SPL = (long)NN * NN;            // score plane
    const long DSQ = (long)DD * DD;

    // fused prep: conv_y | conv_x | pos | prep_u
    k_prep_all<<<dim3(20032), dim3(256), 0, stream>>>(
        x, y, coords, U, S1, S2, pose, xb, yb, yT, UTb, VT, VT + DSQ, P);

    // W_s[i,j] = sum_t U[t,i] S_s[t]^2 U[t,j]  (NT: A=UTb, B=VT_s); z = s
    gemm128<0><<<dim3(DD / 128, DD / 128, 2), dim3(256), 0, stream>>>(
        UTb, VT, W2, DD, DD, 2,
        0L, 0L, DSQ, 0L, DSQ, 0L, 1.0f);

    // x12[s] = xb @ W_s (A bf16 shared across z, W symmetric); z = s.
    // 8-phase (gemm256c 4-phase was +5-7us: m196 confirmed). No XCD swizzle:
    // A-sharers already co-XCD under linear dispatch.
    gemm256<0><<<dim3(BB * NN / 256, DD / 256, 2), dim3(512), 0, stream>>>(
        xb, W2, x12, DD, DD, 2,
        0L, 0L, DSQ, 0L, MBN, 0L, 1.0f, 0);

    // S[b,k] = scale * x_k[b] @ y[b]^T (C f16); z = b*2 + k.
    // SPLIT into two z-halves (256 blocks = exactly 1 CU-round each) to
    // unmask the next-longest kernel in the profile. XCD swizzle on.
    gemm256<1><<<dim3(NN / 256, NN / 256, BB), dim3(512), 0, stream>>>(
        x12, yb, S, DD, NN, 2,
        MBN, BND, 0L, BND, SPL, 2 * SPL, 0.036084391824351615f, 1);
    gemm256<1><<<dim3(NN / 256, NN / 256, BB), dim3(512), 0, stream>>>(
        x12 + 8 * BND, yb + 8 * BND, S + 16 * SPL, DD, NN, 2,
        MBN, BND, 0L, BND, SPL, 2 * SPL, 0.036084391824351615f, 1);

    // softmax + blend + entropy + route; attn_c (bf16) in-place at k=0 plane
    k_route<<<dim3(BB * NN / 2), dim3(128), 0, stream>>>(S, P, gating, temp, heat);

    // out[b] = attn_c[b] @ y[b]   (A bf16 in S k=0 plane, B = yT bf16, C f32)
    gemm256<2><<<dim3(NN / 256, DD / 256, BB), dim3(512), 0, stream>>>(
        S, yT, out, NN, DD, 1,
        0L, 2 * SPL, 0L, BND, 0L, BND, 1.0f, 1);
}